// Round 6
// baseline (311.155 us; speedup 1.0000x reference)
//
#include <hip/hip_runtime.h>

// LinearCrossAttention: B=16, N=4096, M=1024, C_in=C_cond=512, HIDDEN=512
#define KDIM 512

typedef __attribute__((ext_vector_type(8))) short bf16x8;
typedef __attribute__((ext_vector_type(4))) float f32x4;
typedef unsigned short u16;
typedef unsigned int u32;

static __device__ __forceinline__ u16 f2bf(float f) {
  u32 u = __builtin_bit_cast(u32, f);
  u32 r = u + 0x7fffu + ((u >> 16) & 1u);   // round-to-nearest-even
  return (u16)(r >> 16);
}
static __device__ __forceinline__ bf16x8 ld_frag(const u16* p) {
  uint2 lo = *(const uint2*)p;
  uint2 hi = *(const uint2*)(p + 4);
  uint4 u = make_uint4(lo.x, lo.y, hi.x, hi.y);
  return __builtin_bit_cast(bf16x8, u);
}

// ---------------------------------------------------------------------------
// prep: f32 -> bf16 (for Wkv), 8 elems/thread
// ---------------------------------------------------------------------------
__global__ __launch_bounds__(256) void cvt_f32_bf16(
    const float* __restrict__ src, u16* __restrict__ dst, int n8)
{
  int i = blockIdx.x * 256 + threadIdx.x;
  if (i >= n8) return;
  float4 a = *(const float4*)(src + (long)i * 8);
  float4 b = *(const float4*)(src + (long)i * 8 + 4);
  u32 w0 = (u32)f2bf(a.x) | ((u32)f2bf(a.y) << 16);
  u32 w1 = (u32)f2bf(a.z) | ((u32)f2bf(a.w) << 16);
  u32 w2 = (u32)f2bf(b.x) | ((u32)f2bf(b.y) << 16);
  u32 w3 = (u32)f2bf(b.z) | ((u32)f2bf(b.w) << 16);
  *(uint4*)(dst + (long)i * 8) = make_uint4(w0, w1, w2, w3);
}

// ---------------------------------------------------------------------------
// Barrier-free, LDS-free GEMM.
// A: bf16 [rows, 512] row-major.  B: f32 [512, ldn] row-major.  Out: f32/bf16.
// 256 threads = 4 waves; wave w owns a (MIT*16 x 64) output tile at rows
// [mtile + w*MIT*16, ...), cols [ntile, ntile+64).
// A-frags: one global dwordx4 per lane (16 rows x 64B, fully coalesced,
// L2-resident panel).  B-frags: 8 per-lane dword column-walks — one load
// instruction touches 4 k-rows x 16 cols = 4 fully-used 64B sectors; f32 ->
// bf16 packed in-register.  No LDS, no __syncthreads: waves stream
// independently (copy-kernel regime), occupancy VGPR-bound.
// MIT=4: acc 64 VGPR -> 4 waves/SIMD (16 waves/CU).
// MIT=8: acc 128 VGPR -> 2 waves/SIMD, but halves per-block B re-reads.
// ---------------------------------------------------------------------------
template<bool OUT_BF16, bool BIAS, int MIT, int MT, int NT>
__global__ __launch_bounds__(256, (MIT == 4 ? 4 : 2)) void gemm_direct(
    const u16* __restrict__ Ap, long a_bstride,
    const float* __restrict__ Bp, long b_bstride,
    void* __restrict__ Op, long o_bstride,
    const float* __restrict__ bias, int ldn)
{
  const int d = blockIdx.x;
  const int mt = d % MT;
  const int nt = (d / MT) % NT;
  const int b  = d / (MT * NT);
  const long mtile = (long)mt * (4 * MIT * 16);
  const long ntile = (long)nt * 64;

  const int t = threadIdx.x;
  const int lane = t & 63, wv = t >> 6;
  const int lrow = lane & 15, lkh = lane >> 4;

  // per-lane base pointers
  const u16* Aw = Ap + (long)b * a_bstride
                + (mtile + (long)wv * (MIT * 16) + lrow) * KDIM + lkh * 8;
  const float* Bw = Bp + (long)b * b_bstride
                  + (long)(lkh * 8) * ldn + ntile + lrow;

  f32x4 acc[MIT][4] = {};

  for (int kt = 0; kt < KDIM; kt += 32) {
    // ---- A fragments: MIT x dwordx4 (L2-resident) ----
    bf16x8 af[MIT];
    #pragma unroll
    for (int mi = 0; mi < MIT; ++mi)
      af[mi] = *(const bf16x8*)(Aw + (long)mi * 16 * KDIM + kt);
    // ---- B fragments: per-lane column-walk dwords, cvt+pack in-register ----
    bf16x8 bfr[4];
    #pragma unroll
    for (int ni = 0; ni < 4; ++ni) {
      float v[8];
      #pragma unroll
      for (int j = 0; j < 8; ++j)
        v[j] = Bw[(long)(kt + j) * ldn + ni * 16];
      u32 p0 = (u32)f2bf(v[0]) | ((u32)f2bf(v[1]) << 16);
      u32 p1 = (u32)f2bf(v[2]) | ((u32)f2bf(v[3]) << 16);
      u32 p2 = (u32)f2bf(v[4]) | ((u32)f2bf(v[5]) << 16);
      u32 p3 = (u32)f2bf(v[6]) | ((u32)f2bf(v[7]) << 16);
      bfr[ni] = __builtin_bit_cast(bf16x8, make_uint4(p0, p1, p2, p3));
    }
    __builtin_amdgcn_s_setprio(1);
    #pragma unroll
    for (int mi = 0; mi < MIT; ++mi)
      #pragma unroll
      for (int ni = 0; ni < 4; ++ni)
        acc[mi][ni] = __builtin_amdgcn_mfma_f32_16x16x32_bf16(af[mi], bfr[ni], acc[mi][ni], 0, 0, 0);
    __builtin_amdgcn_s_setprio(0);
  }

  // ---- epilogue: scalar stores, 16 lanes x 4B = 64B contiguous per instr ----
  #pragma unroll
  for (int mi = 0; mi < MIT; ++mi) {
    #pragma unroll
    for (int r = 0; r < 4; ++r) {
      long gr = mtile + wv * (MIT * 16) + mi * 16 + lkh * 4 + r;
      float bv = 0.0f;
      if constexpr (BIAS) bv = bias[gr];
      #pragma unroll
      for (int ni = 0; ni < 4; ++ni) {
        long gc = ntile + ni * 16 + lrow;
        float v = acc[mi][ni][r] + bv;
        if constexpr (OUT_BF16)
          ((u16*)Op)[(long)b * o_bstride + gr * ldn + gc] = f2bf(v);
        else
          ((float*)Op)[(long)b * o_bstride + gr * ldn + gc] = v;
      }
    }
  }
}

// ---------------------------------------------------------------------------
// K2: per (b,h): softmax over m of K rows, ctx[d][e] = sum_m Kexp[d][m]*V[e][m]
// ---------------------------------------------------------------------------
__global__ __launch_bounds__(256, 2) void softmax_context(
    const u16* __restrict__ kv, float* __restrict__ ctx)
{
  constexpr int LDE = 132;
  __shared__ float rowmax[64], rowinv[64];
  __shared__ u16 Ke[64 * LDE];
  __shared__ u16 Vs[64 * LDE];
  __shared__ float pr[64 * 68];

  const int bh = blockIdx.x;
  const u16* Kr = kv + (long)(bh >> 3) * (1024 * 1024) + (long)(bh & 7) * (64 * 1024);
  const u16* Vr = Kr + 512 * 1024;

  const int t = threadIdx.x;
  const int lane = t & 63, wv = t >> 6;
  const int lrow = lane & 15, lkh = lane >> 4;
  const int d4 = t >> 2, q4 = t & 3;

  {
    const u16* row = Kr + d4 * 1024 + q4 * 256;
    float mx = -3e38f;
    for (int i = 0; i < 256; i += 8) {
      uint4 v = *(const uint4*)(row + i);
      u32 ws[4] = {v.x, v.y, v.z, v.w};
      #pragma unroll
      for (int j = 0; j < 4; ++j) {
        mx = fmaxf(mx, __builtin_bit_cast(float, ws[j] << 16));
        mx = fmaxf(mx, __builtin_bit_cast(float, ws[j] & 0xffff0000u));
      }
    }
    mx = fmaxf(mx, __shfl_xor(mx, 1));
    mx = fmaxf(mx, __shfl_xor(mx, 2));
    float s = 0.f;
    for (int i = 0; i < 256; i += 8) {
      uint4 v = *(const uint4*)(row + i);
      u32 ws[4] = {v.x, v.y, v.z, v.w};
      #pragma unroll
      for (int j = 0; j < 4; ++j) {
        s += __expf(__builtin_bit_cast(float, ws[j] << 16) - mx);
        s += __expf(__builtin_bit_cast(float, ws[j] & 0xffff0000u) - mx);
      }
    }
    s += __shfl_xor(s, 1);
    s += __shfl_xor(s, 2);
    if (q4 == 0) { rowmax[d4] = mx; rowinv[d4] = 1.f / s; }
  }
  __syncthreads();

  f32x4 cacc[4][4] = {};

  for (int mc = 0; mc < 8; ++mc) {
    {
      int dd = t >> 2, j = t & 3;
      int m0 = mc * 128 + j * 32;
      float mx = rowmax[dd], inv = rowinv[dd];
      const u16* src = Kr + dd * 1024 + m0;
      u16* dst = &Ke[dd * LDE + j * 32];
      #pragma unroll
      for (int cq = 0; cq < 4; ++cq) {
        uint4 v = *(const uint4*)(src + cq * 8);
        u32 in[4] = {v.x, v.y, v.z, v.w};
        u32 out[4];
        #pragma unroll
        for (int j2 = 0; j2 < 4; ++j2) {
          float lo = __builtin_bit_cast(float, in[j2] << 16);
          float hi = __builtin_bit_cast(float, in[j2] & 0xffff0000u);
          out[j2] = (u32)f2bf(__expf(lo - mx) * inv) |
                    ((u32)f2bf(__expf(hi - mx) * inv) << 16);
        }
        *(uint2*)(dst + cq * 8)     = make_uint2(out[0], out[1]);
        *(uint2*)(dst + cq * 8 + 4) = make_uint2(out[2], out[3]);
      }
      const u16* vsrc = Vr + dd * 1024 + m0;
      u16* vdst = &Vs[dd * LDE + j * 32];
      #pragma unroll
      for (int cq = 0; cq < 4; ++cq) {
        uint4 v = *(const uint4*)(vsrc + cq * 8);
        *(uint2*)(vdst + cq * 8)     = make_uint2(v.x, v.y);
        *(uint2*)(vdst + cq * 8 + 4) = make_uint2(v.z, v.w);
      }
    }
    __syncthreads();
    bf16x8 ka[4], vb[4];
    #pragma unroll
    for (int mi = 0; mi < 4; ++mi)
      ka[mi] = ld_frag(&Ke[(mi * 16 + lrow) * LDE + wv * 32 + lkh * 8]);
    #pragma unroll
    for (int ni = 0; ni < 4; ++ni)
      vb[ni] = ld_frag(&Vs[(ni * 16 + lrow) * LDE + wv * 32 + lkh * 8]);
    #pragma unroll
    for (int mi = 0; mi < 4; ++mi)
      #pragma unroll
      for (int ni = 0; ni < 4; ++ni)
        cacc[mi][ni] = __builtin_amdgcn_mfma_f32_16x16x32_bf16(ka[mi], vb[ni], cacc[mi][ni], 0, 0, 0);
    __syncthreads();
  }

  for (int w = 0; w < 4; ++w) {
    if (wv == w) {
      #pragma unroll
      for (int mi = 0; mi < 4; ++mi)
        #pragma unroll
        for (int ni = 0; ni < 4; ++ni)
          #pragma unroll
          for (int r = 0; r < 4; ++r) {
            float* p = &pr[(mi * 16 + lkh * 4 + r) * 68 + (ni * 16 + lrow)];
            float v = cacc[mi][ni][r];
            if (w == 0) *p = v; else *p += v;
          }
    }
    __syncthreads();
  }
  float* cg = ctx + (long)bh * 4096;
  for (int i = 0; i < 16; ++i) {
    int o = t + i * 256;
    cg[o] = 0.125f * pr[(o >> 6) * 68 + (o & 63)];  // fold q-scale
  }
}

// ---------------------------------------------------------------------------
// K3a: U[b][o][h*64+d] = sum_e Wo[o][h*64+e] * ctx[b,h,d,e]
// ---------------------------------------------------------------------------
__global__ __launch_bounds__(256) void compose_u(
    const float* __restrict__ ctx, const float* __restrict__ Wo, u16* __restrict__ U)
{
  __shared__ float cs[16 * 64];
  const int bh = blockIdx.x, dq = blockIdx.y;
  const int b = bh >> 3, h = bh & 7;
  const int t = threadIdx.x;
  const float* cgrp = ctx + (long)bh * 4096 + dq * 16 * 64;
  for (int i = t; i < 1024; i += 256) cs[i] = cgrp[i];
  __syncthreads();
  #pragma unroll
  for (int rep = 0; rep < 2; ++rep) {
    int o = rep * 256 + t;
    const float* wrow = Wo + (long)o * 512 + h * 64;
    float acc[16] = {};
    for (int e = 0; e < 64; ++e) {
      float w = wrow[e];
      #pragma unroll
      for (int dd = 0; dd < 16; ++dd) acc[dd] += w * cs[dd * 64 + e];
    }
    u16* urow = U + (long)b * (512 * 512) + (long)o * 512 + h * 64 + dq * 16;
    #pragma unroll
    for (int dd = 0; dd < 16; ++dd) urow[dd] = f2bf(acc[dd]);
  }
}

// ---------------------------------------------------------------------------
extern "C" void kernel_launch(void* const* d_in, const int* in_sizes, int n_in,
                              void* d_out, int out_size, void* d_ws, size_t ws_size,
                              hipStream_t stream)
{
  const float* x   = (const float*)d_in[0];  // [16, 512, 4096]
  const float* c   = (const float*)d_in[1];  // [16, 512, 1024]
  const float* Wq  = (const float*)d_in[2];  // [512, 512]
  const float* Wkv = (const float*)d_in[3];  // [1024, 512]
  const float* Wo  = (const float*)d_in[4];  // [512, 512]
  const float* bo  = (const float*)d_in[5];  // [512]

  // workspace layout (52.4 MB total)
  char* ws = (char*)d_ws;
  u16*   kv   = (u16*)ws;                      // 16*1024*1024 bf16 = 33.5 MB
  float* ctx  = (float*)(ws + 33554432);       // 16*8*64*64 f32    =  2.1 MB
  u16*   U    = (u16*)(ws + 35651584);         // 16*512*512 bf16   =  8.4 MB
  u16*   Weff = (u16*)(ws + 44040192);         // 16*512*512 bf16   =  8.4 MB
  u16*   Wkvb = (u16*)(ws + 44040192);         // 1 MB, overlaps Weff: consumed by K1
                                               // BEFORE K3b writes Weff

  // K0: Wkv f32 -> bf16
  cvt_f32_bf16<<<dim3(256), 256, 0, stream>>>(Wkv, Wkvb, 65536);
  // K1: kv[b] = Wkv @ c[b]   MIT=8 (512-row blocks, halves c L2-dup), MT=2, NT=16
  gemm_direct<true, false, 8, 2, 16><<<dim3(2 * 16 * 16), 256, 0, stream>>>(
      Wkvb, 0, c, 512L * 1024, kv, 1024L * 1024, nullptr, 1024);
  // K2: softmax + context
  softmax_context<<<dim3(128), 256, 0, stream>>>(kv, ctx);
  // K3a: U = scale * Wo_h @ ctx_h^T
  compose_u<<<dim3(128, 4), 256, 0, stream>>>(ctx, Wo, U);
  // K3b: Weff[b] = U[b] @ Wq   MIT=4, MT=2, NT=8
  gemm_direct<true, false, 4, 2, 8><<<dim3(2 * 8 * 16), 256, 0, stream>>>(
      U, 512L * 512, Wq, 0, Weff, 512L * 512, nullptr, 512);
  // K4: Y[b] = Weff[b] @ x[b] + bo   MIT=4 (16 waves/CU), MT=2, NT=64
  gemm_direct<false, true, 4, 2, 64><<<dim3(2 * 64 * 16), 256, 0, stream>>>(
      Weff, 512L * 512, x, 512L * 4096, d_out, 512L * 4096, bo, 4096);
}

// Round 7
// 310.068 us; speedup vs baseline: 1.0035x; 1.0035x over previous
//
#include <hip/hip_runtime.h>

// LinearCrossAttention: B=16, N=4096, M=1024, C_in=C_cond=512, HIDDEN=512
#define KDIM 512

typedef __attribute__((ext_vector_type(8))) short bf16x8;
typedef __attribute__((ext_vector_type(4))) float f32x4;
typedef unsigned short u16;
typedef unsigned int u32;

static __device__ __forceinline__ u16 f2bf(float f) {
  u32 u = __builtin_bit_cast(u32, f);
  u32 r = u + 0x7fffu + ((u >> 16) & 1u);   // round-to-nearest-even
  return (u16)(r >> 16);
}
static __device__ __forceinline__ bf16x8 ld_frag(const u16* p) {
  uint2 lo = *(const uint2*)p;
  uint2 hi = *(const uint2*)(p + 4);
  uint4 u = make_uint4(lo.x, lo.y, hi.x, hi.y);
  return __builtin_bit_cast(bf16x8, u);
}

// ---------------------------------------------------------------------------
// prep: f32 -> bf16 (for Wkv), 8 elems/thread
// ---------------------------------------------------------------------------
__global__ __launch_bounds__(256) void cvt_f32_bf16(
    const float* __restrict__ src, u16* __restrict__ dst, int n8)
{
  int i = blockIdx.x * 256 + threadIdx.x;
  if (i >= n8) return;
  float4 a = *(const float4*)(src + (long)i * 8);
  float4 b = *(const float4*)(src + (long)i * 8 + 4);
  u32 w0 = (u32)f2bf(a.x) | ((u32)f2bf(a.y) << 16);
  u32 w1 = (u32)f2bf(a.z) | ((u32)f2bf(a.w) << 16);
  u32 w2 = (u32)f2bf(b.x) | ((u32)f2bf(b.y) << 16);
  u32 w3 = (u32)f2bf(b.z) | ((u32)f2bf(b.w) << 16);
  *(uint4*)(dst + (long)i * 8) = make_uint4(w0, w1, w2, w3);
}

// ---------------------------------------------------------------------------
// Barrier-free, LDS-free GEMM.
// A: bf16 [rows, 512] row-major.  B: f32 [512, ldn] row-major.  Out: f32/bf16.
// 256 threads = 4 waves; wave w owns a (MIT*16 x 64) output tile at rows
// [mtile + w*MIT*16, ...), cols [ntile, ntile+64).
// A-frags: one global dwordx4 per lane (16 rows x 64B, fully coalesced,
// L2-resident panel).  B-frags: 8 per-lane dword column-walks — one load
// instruction touches 4 k-rows x 16 cols = 4 fully-used 64B sectors; f32 ->
// bf16 packed in-register.  No LDS, no __syncthreads: waves stream
// independently (copy-kernel regime), occupancy VGPR-bound.
// MIT=4: acc 64 VGPR -> 4 waves/SIMD (16 waves/CU).
// MIT=8: acc 128 VGPR -> 2 waves/SIMD, but halves per-block B re-reads.
// ---------------------------------------------------------------------------
template<bool OUT_BF16, bool BIAS, int MIT, int MT, int NT>
__global__ __launch_bounds__(256, (MIT == 4 ? 4 : 2)) void gemm_direct(
    const u16* __restrict__ Ap, long a_bstride,
    const float* __restrict__ Bp, long b_bstride,
    void* __restrict__ Op, long o_bstride,
    const float* __restrict__ bias, int ldn)
{
  const int d = blockIdx.x;
  const int mt = d % MT;
  const int nt = (d / MT) % NT;
  const int b  = d / (MT * NT);
  const long mtile = (long)mt * (4 * MIT * 16);
  const long ntile = (long)nt * 64;

  const int t = threadIdx.x;
  const int lane = t & 63, wv = t >> 6;
  const int lrow = lane & 15, lkh = lane >> 4;

  // per-lane base pointers
  const u16* Aw = Ap + (long)b * a_bstride
                + (mtile + (long)wv * (MIT * 16) + lrow) * KDIM + lkh * 8;
  const float* Bw = Bp + (long)b * b_bstride
                  + (long)(lkh * 8) * ldn + ntile + lrow;

  f32x4 acc[MIT][4] = {};

  for (int kt = 0; kt < KDIM; kt += 32) {
    // ---- A fragments: MIT x dwordx4 (L2-resident) ----
    bf16x8 af[MIT];
    #pragma unroll
    for (int mi = 0; mi < MIT; ++mi)
      af[mi] = *(const bf16x8*)(Aw + (long)mi * 16 * KDIM + kt);
    // ---- B fragments: per-lane column-walk dwords, cvt+pack in-register ----
    bf16x8 bfr[4];
    #pragma unroll
    for (int ni = 0; ni < 4; ++ni) {
      float v[8];
      #pragma unroll
      for (int j = 0; j < 8; ++j)
        v[j] = Bw[(long)(kt + j) * ldn + ni * 16];
      u32 p0 = (u32)f2bf(v[0]) | ((u32)f2bf(v[1]) << 16);
      u32 p1 = (u32)f2bf(v[2]) | ((u32)f2bf(v[3]) << 16);
      u32 p2 = (u32)f2bf(v[4]) | ((u32)f2bf(v[5]) << 16);
      u32 p3 = (u32)f2bf(v[6]) | ((u32)f2bf(v[7]) << 16);
      bfr[ni] = __builtin_bit_cast(bf16x8, make_uint4(p0, p1, p2, p3));
    }
    __builtin_amdgcn_s_setprio(1);
    #pragma unroll
    for (int mi = 0; mi < MIT; ++mi)
      #pragma unroll
      for (int ni = 0; ni < 4; ++ni)
        acc[mi][ni] = __builtin_amdgcn_mfma_f32_16x16x32_bf16(af[mi], bfr[ni], acc[mi][ni], 0, 0, 0);
    __builtin_amdgcn_s_setprio(0);
  }

  // ---- epilogue: scalar stores, 16 lanes x 4B = 64B contiguous per instr ----
  #pragma unroll
  for (int mi = 0; mi < MIT; ++mi) {
    #pragma unroll
    for (int r = 0; r < 4; ++r) {
      long gr = mtile + wv * (MIT * 16) + mi * 16 + lkh * 4 + r;
      float bv = 0.0f;
      if constexpr (BIAS) bv = bias[gr];
      #pragma unroll
      for (int ni = 0; ni < 4; ++ni) {
        long gc = ntile + ni * 16 + lrow;
        float v = acc[mi][ni][r] + bv;
        if constexpr (OUT_BF16)
          ((u16*)Op)[(long)b * o_bstride + gr * ldn + gc] = f2bf(v);
        else
          ((float*)Op)[(long)b * o_bstride + gr * ldn + gc] = v;
      }
    }
  }
}

// ---------------------------------------------------------------------------
// K2: per (b,h): softmax over m of K rows, ctx[d][e] = sum_m Kexp[d][m]*V[e][m]
// ---------------------------------------------------------------------------
__global__ __launch_bounds__(256, 2) void softmax_context(
    const u16* __restrict__ kv, float* __restrict__ ctx)
{
  constexpr int LDE = 132;
  __shared__ float rowmax[64], rowinv[64];
  __shared__ u16 Ke[64 * LDE];
  __shared__ u16 Vs[64 * LDE];
  __shared__ float pr[64 * 68];

  const int bh = blockIdx.x;
  const u16* Kr = kv + (long)(bh >> 3) * (1024 * 1024) + (long)(bh & 7) * (64 * 1024);
  const u16* Vr = Kr + 512 * 1024;

  const int t = threadIdx.x;
  const int lane = t & 63, wv = t >> 6;
  const int lrow = lane & 15, lkh = lane >> 4;
  const int d4 = t >> 2, q4 = t & 3;

  {
    const u16* row = Kr + d4 * 1024 + q4 * 256;
    float mx = -3e38f;
    for (int i = 0; i < 256; i += 8) {
      uint4 v = *(const uint4*)(row + i);
      u32 ws[4] = {v.x, v.y, v.z, v.w};
      #pragma unroll
      for (int j = 0; j < 4; ++j) {
        mx = fmaxf(mx, __builtin_bit_cast(float, ws[j] << 16));
        mx = fmaxf(mx, __builtin_bit_cast(float, ws[j] & 0xffff0000u));
      }
    }
    mx = fmaxf(mx, __shfl_xor(mx, 1));
    mx = fmaxf(mx, __shfl_xor(mx, 2));
    float s = 0.f;
    for (int i = 0; i < 256; i += 8) {
      uint4 v = *(const uint4*)(row + i);
      u32 ws[4] = {v.x, v.y, v.z, v.w};
      #pragma unroll
      for (int j = 0; j < 4; ++j) {
        s += __expf(__builtin_bit_cast(float, ws[j] << 16) - mx);
        s += __expf(__builtin_bit_cast(float, ws[j] & 0xffff0000u) - mx);
      }
    }
    s += __shfl_xor(s, 1);
    s += __shfl_xor(s, 2);
    if (q4 == 0) { rowmax[d4] = mx; rowinv[d4] = 1.f / s; }
  }
  __syncthreads();

  f32x4 cacc[4][4] = {};

  for (int mc = 0; mc < 8; ++mc) {
    {
      int dd = t >> 2, j = t & 3;
      int m0 = mc * 128 + j * 32;
      float mx = rowmax[dd], inv = rowinv[dd];
      const u16* src = Kr + dd * 1024 + m0;
      u16* dst = &Ke[dd * LDE + j * 32];
      #pragma unroll
      for (int cq = 0; cq < 4; ++cq) {
        uint4 v = *(const uint4*)(src + cq * 8);
        u32 in[4] = {v.x, v.y, v.z, v.w};
        u32 out[4];
        #pragma unroll
        for (int j2 = 0; j2 < 4; ++j2) {
          float lo = __builtin_bit_cast(float, in[j2] << 16);
          float hi = __builtin_bit_cast(float, in[j2] & 0xffff0000u);
          out[j2] = (u32)f2bf(__expf(lo - mx) * inv) |
                    ((u32)f2bf(__expf(hi - mx) * inv) << 16);
        }
        *(uint2*)(dst + cq * 8)     = make_uint2(out[0], out[1]);
        *(uint2*)(dst + cq * 8 + 4) = make_uint2(out[2], out[3]);
      }
      const u16* vsrc = Vr + dd * 1024 + m0;
      u16* vdst = &Vs[dd * LDE + j * 32];
      #pragma unroll
      for (int cq = 0; cq < 4; ++cq) {
        uint4 v = *(const uint4*)(vsrc + cq * 8);
        *(uint2*)(vdst + cq * 8)     = make_uint2(v.x, v.y);
        *(uint2*)(vdst + cq * 8 + 4) = make_uint2(v.z, v.w);
      }
    }
    __syncthreads();
    bf16x8 ka[4], vb[4];
    #pragma unroll
    for (int mi = 0; mi < 4; ++mi)
      ka[mi] = ld_frag(&Ke[(mi * 16 + lrow) * LDE + wv * 32 + lkh * 8]);
    #pragma unroll
    for (int ni = 0; ni < 4; ++ni)
      vb[ni] = ld_frag(&Vs[(ni * 16 + lrow) * LDE + wv * 32 + lkh * 8]);
    #pragma unroll
    for (int mi = 0; mi < 4; ++mi)
      #pragma unroll
      for (int ni = 0; ni < 4; ++ni)
        cacc[mi][ni] = __builtin_amdgcn_mfma_f32_16x16x32_bf16(ka[mi], vb[ni], cacc[mi][ni], 0, 0, 0);
    __syncthreads();
  }

  for (int w = 0; w < 4; ++w) {
    if (wv == w) {
      #pragma unroll
      for (int mi = 0; mi < 4; ++mi)
        #pragma unroll
        for (int ni = 0; ni < 4; ++ni)
          #pragma unroll
          for (int r = 0; r < 4; ++r) {
            float* p = &pr[(mi * 16 + lkh * 4 + r) * 68 + (ni * 16 + lrow)];
            float v = cacc[mi][ni][r];
            if (w == 0) *p = v; else *p += v;
          }
    }
    __syncthreads();
  }
  float* cg = ctx + (long)bh * 4096;
  for (int i = 0; i < 16; ++i) {
    int o = t + i * 256;
    cg[o] = 0.125f * pr[(o >> 6) * 68 + (o & 63)];  // fold q-scale
  }
}

// ---------------------------------------------------------------------------
// K3a: U[b][o][h*64+d] = sum_e Wo[o][h*64+e] * ctx[b,h,d,e]
// ---------------------------------------------------------------------------
__global__ __launch_bounds__(256) void compose_u(
    const float* __restrict__ ctx, const float* __restrict__ Wo, u16* __restrict__ U)
{
  __shared__ float cs[16 * 64];
  const int bh = blockIdx.x, dq = blockIdx.y;
  const int b = bh >> 3, h = bh & 7;
  const int t = threadIdx.x;
  const float* cgrp = ctx + (long)bh * 4096 + dq * 16 * 64;
  for (int i = t; i < 1024; i += 256) cs[i] = cgrp[i];
  __syncthreads();
  #pragma unroll
  for (int rep = 0; rep < 2; ++rep) {
    int o = rep * 256 + t;
    const float* wrow = Wo + (long)o * 512 + h * 64;
    float acc[16] = {};
    for (int e = 0; e < 64; ++e) {
      float w = wrow[e];
      #pragma unroll
      for (int dd = 0; dd < 16; ++dd) acc[dd] += w * cs[dd * 64 + e];
    }
    u16* urow = U + (long)b * (512 * 512) + (long)o * 512 + h * 64 + dq * 16;
    #pragma unroll
    for (int dd = 0; dd < 16; ++dd) urow[dd] = f2bf(acc[dd]);
  }
}

// ---------------------------------------------------------------------------
extern "C" void kernel_launch(void* const* d_in, const int* in_sizes, int n_in,
                              void* d_out, int out_size, void* d_ws, size_t ws_size,
                              hipStream_t stream)
{
  const float* x   = (const float*)d_in[0];  // [16, 512, 4096]
  const float* c   = (const float*)d_in[1];  // [16, 512, 1024]
  const float* Wq  = (const float*)d_in[2];  // [512, 512]
  const float* Wkv = (const float*)d_in[3];  // [1024, 512]
  const float* Wo  = (const float*)d_in[4];  // [512, 512]
  const float* bo  = (const float*)d_in[5];  // [512]

  // workspace layout (52.4 MB total)
  char* ws = (char*)d_ws;
  u16*   kv   = (u16*)ws;                      // 16*1024*1024 bf16 = 33.5 MB
  float* ctx  = (float*)(ws + 33554432);       // 16*8*64*64 f32    =  2.1 MB
  u16*   U    = (u16*)(ws + 35651584);         // 16*512*512 bf16   =  8.4 MB
  u16*   Weff = (u16*)(ws + 44040192);         // 16*512*512 bf16   =  8.4 MB
  u16*   Wkvb = (u16*)(ws + 44040192);         // 1 MB, overlaps Weff: consumed by K1
                                               // BEFORE K3b writes Weff

  // K0: Wkv f32 -> bf16
  cvt_f32_bf16<<<dim3(256), 256, 0, stream>>>(Wkv, Wkvb, 65536);
  // K1: kv[b] = Wkv @ c[b]   MIT=8 (512-row blocks, halves c L2-dup), MT=2, NT=16
  gemm_direct<true, false, 8, 2, 16><<<dim3(2 * 16 * 16), 256, 0, stream>>>(
      Wkvb, 0, c, 512L * 1024, kv, 1024L * 1024, nullptr, 1024);
  // K2: softmax + context
  softmax_context<<<dim3(128), 256, 0, stream>>>(kv, ctx);
  // K3a: U = scale * Wo_h @ ctx_h^T
  compose_u<<<dim3(128, 4), 256, 0, stream>>>(ctx, Wo, U);
  // K3b: Weff[b] = U[b] @ Wq   MIT=4, MT=2, NT=8
  gemm_direct<true, false, 4, 2, 8><<<dim3(2 * 8 * 16), 256, 0, stream>>>(
      U, 512L * 512, Wq, 0, Weff, 512L * 512, nullptr, 512);
  // K4: Y[b] = Weff[b] @ x[b] + bo   MIT=4 (16 waves/CU), MT=2, NT=64
  gemm_direct<false, true, 4, 2, 64><<<dim3(2 * 64 * 16), 256, 0, stream>>>(
      Weff, 512L * 512, x, 512L * 4096, d_out, 512L * 4096, bo, 4096);
}

// Round 8
// 176.235 us; speedup vs baseline: 1.7656x; 1.7594x over previous
//
#include <hip/hip_runtime.h>

// LinearCrossAttention: B=16, N=4096, M=1024, C_in=C_cond=512, HIDDEN=512
#define KDIM 512

typedef __attribute__((ext_vector_type(8))) short bf16x8;
typedef __attribute__((ext_vector_type(4))) float f32x4;
typedef unsigned short u16;
typedef unsigned int u32;

static __device__ __forceinline__ u16 f2bf(float f) {
  u32 u = __builtin_bit_cast(u32, f);
  u32 r = u + 0x7fffu + ((u >> 16) & 1u);   // round-to-nearest-even
  return (u16)(r >> 16);
}
static __device__ __forceinline__ bf16x8 ld_frag(const u16* p) {
  uint2 lo = *(const uint2*)p;
  uint2 hi = *(const uint2*)(p + 4);
  uint4 u = make_uint4(lo.x, lo.y, hi.x, hi.y);
  return __builtin_bit_cast(bf16x8, u);
}

// ---------------------------------------------------------------------------
// prep: f32 -> bf16 (for Wkv), 8 elems/thread
// ---------------------------------------------------------------------------
__global__ __launch_bounds__(256) void cvt_f32_bf16(
    const float* __restrict__ src, u16* __restrict__ dst, int n8)
{
  int i = blockIdx.x * 256 + threadIdx.x;
  if (i >= n8) return;
  float4 a = *(const float4*)(src + (long)i * 8);
  float4 b = *(const float4*)(src + (long)i * 8 + 4);
  u32 w0 = (u32)f2bf(a.x) | ((u32)f2bf(a.y) << 16);
  u32 w1 = (u32)f2bf(a.z) | ((u32)f2bf(a.w) << 16);
  u32 w2 = (u32)f2bf(b.x) | ((u32)f2bf(b.y) << 16);
  u32 w3 = (u32)f2bf(b.z) | ((u32)f2bf(b.w) << 16);
  *(uint4*)(dst + (long)i * 8) = make_uint4(w0, w1, w2, w3);
}

// ---------------------------------------------------------------------------
// Pipelined GEMM: BM=512, BN=128, BK=32 (= MFMA native K), 512 thr = 8 waves
// (4M x 2N), per-wave 128x64 output (acc = 128 VGPR).
// A: bf16 [*,512] row-major.  B: f32 [512, ldn] row-major, transposed+cvt to
// bf16 in LDS.  x (B of K4) is read from HBM EXACTLY ONCE (BM = full M).
// Schedule (T3-minimum with reg staging):
//   - LDS double-buffered: ONE barrier per K-step (stage k+1 -> other buffer
//     overlaps MFMA of step k).
//   - depth-2 register prefetch, statically-named sets (rule #20): loads for
//     step k+2 issue before MFMA of step k -> ~2 steps of latency cover; the
//     ds_write's vmcnt is compiler-counted on only its own loads (T4).
// LDS rows padded to 36 u16 (72B stride — same proven-conflict-free family
// as the 68-pad at BK=64).  B loads: 4 consecutive lanes = one full 64B line
// (sector-exact); k-group XOR-spread keeps staging writes <=2-way.
// ---------------------------------------------------------------------------
#define A0OFF 0
#define A1OFF 18432
#define B0OFF 36864
#define B1OFF 41472

#define P_LOADA(pa, kt) { _Pragma("unroll") \
  for (int i_ = 0; i_ < 4; ++i_) \
    pa[i_] = *(const uint4*)(Ab + (long)(arow + i_ * 128) * KDIM + (kt) + ac * 8); }

#define P_LOADB(q0, q1, kt) { \
  q0 = *(const float4*)(Bb + (long)((kt) + krow)     * ldn + nq * 4); \
  q1 = *(const float4*)(Bb + (long)((kt) + krow + 1) * ldn + nq * 4); }

#define P_STAGE(pa, q0, q1, ab, bb) { \
  _Pragma("unroll") for (int i_ = 0; i_ < 4; ++i_) { \
    u16* d_ = &lds[(ab) + (arow + i_ * 128) * 36 + ac * 8]; \
    *(uint2*)d_       = make_uint2(pa[i_].x, pa[i_].y); \
    *(uint2*)(d_ + 4) = make_uint2(pa[i_].z, pa[i_].w); } \
  float f0_[4] = {q0.x, q0.y, q0.z, q0.w}; \
  float f1_[4] = {q1.x, q1.y, q1.z, q1.w}; \
  _Pragma("unroll") for (int j_ = 0; j_ < 4; ++j_) { \
    u32 w_ = (u32)f2bf(f0_[j_]) | ((u32)f2bf(f1_[j_]) << 16); \
    *(u32*)&lds[(bb) + (nq * 4 + j_) * 36 + krow] = w_; } }

#define P_MFMA(ab, bb) { \
  bf16x8 bfr_[4]; \
  _Pragma("unroll") for (int ni_ = 0; ni_ < 4; ++ni_) \
    bfr_[ni_] = ld_frag(&lds[(bb) + (wn * 64 + ni_ * 16 + lrow) * 36 + lkh * 8]); \
  __builtin_amdgcn_s_setprio(1); \
  _Pragma("unroll") for (int mi_ = 0; mi_ < 8; ++mi_) { \
    bf16x8 af_ = ld_frag(&lds[(ab) + (wm * 128 + mi_ * 16 + lrow) * 36 + lkh * 8]); \
    _Pragma("unroll") for (int ni_ = 0; ni_ < 4; ++ni_) \
      acc[mi_][ni_] = __builtin_amdgcn_mfma_f32_16x16x32_bf16(af_, bfr_[ni_], acc[mi_][ni_], 0, 0, 0); } \
  __builtin_amdgcn_s_setprio(0); }

template<bool OUT_BF16, bool BIAS, int MT, int NT>
__global__ __launch_bounds__(512, 2) void gemm_p(
    const u16* __restrict__ Ap, long a_bstride,
    const float* __restrict__ Bp, long b_bstride,
    void* __restrict__ Op, long o_bstride,
    const float* __restrict__ bias, int ldn)
{
  __shared__ u16 lds[46080];               // 92.16 KB: A dbuf 2x36.9 + B dbuf 2x9.2

  const int d = blockIdx.x;                // mt innermost: B-slice sharers adjacent
  const int mt = d % MT;
  const int nt = (d / MT) % NT;
  const int b  = d / (MT * NT);
  const long mtile = (long)mt * 512;
  const long ntile = (long)nt * 128;
  const u16* Ab = Ap + (long)b * a_bstride + mtile * KDIM;
  const float* Bb = Bp + (long)b * b_bstride + ntile;

  const int t = threadIdx.x;
  const int lane = t & 63, wv = t >> 6;
  const int wm = wv >> 1, wn = wv & 1;     // 4 x 2 wave grid
  const int lrow = lane & 15, lkh = lane >> 4;

  // staging maps
  const int arow = t >> 2, ac = t & 3;     // A: rows arow+128i, 16B granule ac
  const int nq = t & 31;                   // B: 4-col group (128 cols)
  const int hi = (t >> 8) & 1;
  const int kq = ((t >> 5) & 7) ^ ((t >> 2) & 7);  // XOR-spread 4-row group
  const int krow = kq * 4 + hi * 2;        // this thread's adjacent k-row pair

  f32x4 acc[8][4] = {};
  uint4 pa0[4], pa1[4];
  float4 b0a, b0b, b1a, b1b;

  // ---- prologue: fill both reg sets, stage step 0 ----
  P_LOADA(pa0, 0)  P_LOADB(b0a, b0b, 0)
  P_LOADA(pa1, 32) P_LOADB(b1a, b1b, 32)
  P_STAGE(pa0, b0a, b0b, A0OFF, B0OFF)
  __syncthreads();

  for (int s2 = 0; s2 < 8; ++s2) {         // 16 K-steps as even/odd pairs
    const int kt = s2 * 64;
    // even step: compute buf0; prefetch k+2 into set0; stage set1 -> buf1
    if (s2 < 7) { P_LOADA(pa0, kt + 64) P_LOADB(b0a, b0b, kt + 64) }
    P_MFMA(A0OFF, B0OFF)
    P_STAGE(pa1, b1a, b1b, A1OFF, B1OFF)
    __syncthreads();
    // odd step: compute buf1; prefetch k+2 into set1; stage set0 -> buf0
    if (s2 < 7) { P_LOADA(pa1, kt + 96) P_LOADB(b1a, b1b, kt + 96) }
    P_MFMA(A1OFF, B1OFF)
    if (s2 < 7) {
      P_STAGE(pa0, b0a, b0b, A0OFF, B0OFF)
      __syncthreads();
    }
  }

  // ---- epilogue: scalar stores, 16 lanes x 4B = 64B contiguous per instr ----
  #pragma unroll
  for (int mi = 0; mi < 8; ++mi) {
    #pragma unroll
    for (int r = 0; r < 4; ++r) {
      long gr = mtile + wm * 128 + mi * 16 + lkh * 4 + r;
      float bv = 0.0f;
      if constexpr (BIAS) bv = bias[gr];
      #pragma unroll
      for (int ni = 0; ni < 4; ++ni) {
        long gc = ntile + wn * 64 + ni * 16 + lrow;
        float v = acc[mi][ni][r] + bv;
        if constexpr (OUT_BF16)
          ((u16*)Op)[(long)b * o_bstride + gr * ldn + gc] = f2bf(v);
        else
          ((float*)Op)[(long)b * o_bstride + gr * ldn + gc] = v;
      }
    }
  }
}

// ---------------------------------------------------------------------------
// K2: per (b,h): softmax over m of K rows, ctx[d][e] = sum_m Kexp[d][m]*V[e][m]
// ---------------------------------------------------------------------------
__global__ __launch_bounds__(256, 2) void softmax_context(
    const u16* __restrict__ kv, float* __restrict__ ctx)
{
  constexpr int LDE = 132;
  __shared__ float rowmax[64], rowinv[64];
  __shared__ u16 Ke[64 * LDE];
  __shared__ u16 Vs[64 * LDE];
  __shared__ float pr[64 * 68];

  const int bh = blockIdx.x;
  const u16* Kr = kv + (long)(bh >> 3) * (1024 * 1024) + (long)(bh & 7) * (64 * 1024);
  const u16* Vr = Kr + 512 * 1024;

  const int t = threadIdx.x;
  const int lane = t & 63, wv = t >> 6;
  const int lrow = lane & 15, lkh = lane >> 4;
  const int d4 = t >> 2, q4 = t & 3;

  {
    const u16* row = Kr + d4 * 1024 + q4 * 256;
    float mx = -3e38f;
    for (int i = 0; i < 256; i += 8) {
      uint4 v = *(const uint4*)(row + i);
      u32 ws[4] = {v.x, v.y, v.z, v.w};
      #pragma unroll
      for (int j = 0; j < 4; ++j) {
        mx = fmaxf(mx, __builtin_bit_cast(float, ws[j] << 16));
        mx = fmaxf(mx, __builtin_bit_cast(float, ws[j] & 0xffff0000u));
      }
    }
    mx = fmaxf(mx, __shfl_xor(mx, 1));
    mx = fmaxf(mx, __shfl_xor(mx, 2));
    float s = 0.f;
    for (int i = 0; i < 256; i += 8) {
      uint4 v = *(const uint4*)(row + i);
      u32 ws[4] = {v.x, v.y, v.z, v.w};
      #pragma unroll
      for (int j = 0; j < 4; ++j) {
        s += __expf(__builtin_bit_cast(float, ws[j] << 16) - mx);
        s += __expf(__builtin_bit_cast(float, ws[j] & 0xffff0000u) - mx);
      }
    }
    s += __shfl_xor(s, 1);
    s += __shfl_xor(s, 2);
    if (q4 == 0) { rowmax[d4] = mx; rowinv[d4] = 1.f / s; }
  }
  __syncthreads();

  f32x4 cacc[4][4] = {};

  for (int mc = 0; mc < 8; ++mc) {
    {
      int dd = t >> 2, j = t & 3;
      int m0 = mc * 128 + j * 32;
      float mx = rowmax[dd], inv = rowinv[dd];
      const u16* src = Kr + dd * 1024 + m0;
      u16* dst = &Ke[dd * LDE + j * 32];
      #pragma unroll
      for (int cq = 0; cq < 4; ++cq) {
        uint4 v = *(const uint4*)(src + cq * 8);
        u32 in[4] = {v.x, v.y, v.z, v.w};
        u32 out[4];
        #pragma unroll
        for (int j2 = 0; j2 < 4; ++j2) {
          float lo = __builtin_bit_cast(float, in[j2] << 16);
          float hif = __builtin_bit_cast(float, in[j2] & 0xffff0000u);
          out[j2] = (u32)f2bf(__expf(lo - mx) * inv) |
                    ((u32)f2bf(__expf(hif - mx) * inv) << 16);
        }
        *(uint2*)(dst + cq * 8)     = make_uint2(out[0], out[1]);
        *(uint2*)(dst + cq * 8 + 4) = make_uint2(out[2], out[3]);
      }
      const u16* vsrc = Vr + dd * 1024 + m0;
      u16* vdst = &Vs[dd * LDE + j * 32];
      #pragma unroll
      for (int cq = 0; cq < 4; ++cq) {
        uint4 v = *(const uint4*)(vsrc + cq * 8);
        *(uint2*)(vdst + cq * 8)     = make_uint2(v.x, v.y);
        *(uint2*)(vdst + cq * 8 + 4) = make_uint2(v.z, v.w);
      }
    }
    __syncthreads();
    bf16x8 ka[4], vb[4];
    #pragma unroll
    for (int mi = 0; mi < 4; ++mi)
      ka[mi] = ld_frag(&Ke[(mi * 16 + lrow) * LDE + wv * 32 + lkh * 8]);
    #pragma unroll
    for (int ni = 0; ni < 4; ++ni)
      vb[ni] = ld_frag(&Vs[(ni * 16 + lrow) * LDE + wv * 32 + lkh * 8]);
    #pragma unroll
    for (int mi = 0; mi < 4; ++mi)
      #pragma unroll
      for (int ni = 0; ni < 4; ++ni)
        cacc[mi][ni] = __builtin_amdgcn_mfma_f32_16x16x32_bf16(ka[mi], vb[ni], cacc[mi][ni], 0, 0, 0);
    __syncthreads();
  }

  for (int w = 0; w < 4; ++w) {
    if (wv == w) {
      #pragma unroll
      for (int mi = 0; mi < 4; ++mi)
        #pragma unroll
        for (int ni = 0; ni < 4; ++ni)
          #pragma unroll
          for (int r = 0; r < 4; ++r) {
            float* p = &pr[(mi * 16 + lkh * 4 + r) * 68 + (ni * 16 + lrow)];
            float v = cacc[mi][ni][r];
            if (w == 0) *p = v; else *p += v;
          }
    }
    __syncthreads();
  }
  float* cg = ctx + (long)bh * 4096;
  for (int i = 0; i < 16; ++i) {
    int o = t + i * 256;
    cg[o] = 0.125f * pr[(o >> 6) * 68 + (o & 63)];  // fold q-scale
  }
}

// ---------------------------------------------------------------------------
// K3a: U[b][o][h*64+d] = sum_e Wo[o][h*64+e] * ctx[b,h,d,e]
// ---------------------------------------------------------------------------
__global__ __launch_bounds__(256) void compose_u(
    const float* __restrict__ ctx, const float* __restrict__ Wo, u16* __restrict__ U)
{
  __shared__ float cs[16 * 64];
  const int bh = blockIdx.x, dq = blockIdx.y;
  const int b = bh >> 3, h = bh & 7;
  const int t = threadIdx.x;
  const float* cgrp = ctx + (long)bh * 4096 + dq * 16 * 64;
  for (int i = t; i < 1024; i += 256) cs[i] = cgrp[i];
  __syncthreads();
  #pragma unroll
  for (int rep = 0; rep < 2; ++rep) {
    int o = rep * 256 + t;
    const float* wrow = Wo + (long)o * 512 + h * 64;
    float acc[16] = {};
    for (int e = 0; e < 64; ++e) {
      float w = wrow[e];
      #pragma unroll
      for (int dd = 0; dd < 16; ++dd) acc[dd] += w * cs[dd * 64 + e];
    }
    u16* urow = U + (long)b * (512 * 512) + (long)o * 512 + h * 64 + dq * 16;
    #pragma unroll
    for (int dd = 0; dd < 16; ++dd) urow[dd] = f2bf(acc[dd]);
  }
}

// ---------------------------------------------------------------------------
extern "C" void kernel_launch(void* const* d_in, const int* in_sizes, int n_in,
                              void* d_out, int out_size, void* d_ws, size_t ws_size,
                              hipStream_t stream)
{
  const float* x   = (const float*)d_in[0];  // [16, 512, 4096]
  const float* c   = (const float*)d_in[1];  // [16, 512, 1024]
  const float* Wq  = (const float*)d_in[2];  // [512, 512]
  const float* Wkv = (const float*)d_in[3];  // [1024, 512]
  const float* Wo  = (const float*)d_in[4];  // [512, 512]
  const float* bo  = (const float*)d_in[5];  // [512]

  // workspace layout (52.4 MB total)
  char* ws = (char*)d_ws;
  u16*   kv   = (u16*)ws;                      // 16*1024*1024 bf16 = 33.5 MB
  float* ctx  = (float*)(ws + 33554432);       // 16*8*64*64 f32    =  2.1 MB
  u16*   U    = (u16*)(ws + 35651584);         // 16*512*512 bf16   =  8.4 MB
  u16*   Weff = (u16*)(ws + 44040192);         // 16*512*512 bf16   =  8.4 MB
  u16*   Wkvb = (u16*)(ws + 44040192);         // 1 MB, overlaps Weff: consumed by K1
                                               // BEFORE K3b writes Weff

  // K0: Wkv f32 -> bf16
  cvt_f32_bf16<<<dim3(256), 256, 0, stream>>>(Wkv, Wkvb, 65536);
  // K1: kv[b] = Wkv @ c[b]        MT=2, NT=8  -> 256 blocks
  gemm_p<true, false, 2, 8><<<dim3(2 * 8 * 16), 512, 0, stream>>>(
      Wkvb, 0, c, 512L * 1024, kv, 1024L * 1024, nullptr, 1024);
  // K2: softmax + context
  softmax_context<<<dim3(128), 256, 0, stream>>>(kv, ctx);
  // K3a: U = scale * Wo_h @ ctx_h^T
  compose_u<<<dim3(128, 4), 256, 0, stream>>>(ctx, Wo, U);
  // K3b: Weff[b] = U[b] @ Wq      MT=1, NT=4  -> 64 blocks
  gemm_p<true, false, 1, 4><<<dim3(1 * 4 * 16), 512, 0, stream>>>(
      U, 512L * 512, Wq, 0, Weff, 512L * 512, nullptr, 512);
  // K4: Y[b] = Weff[b] @ x[b] + bo   MT=1 (x read once), NT=32 -> 512 blocks
  gemm_p<false, true, 1, 32><<<dim3(1 * 32 * 16), 512, 0, stream>>>(
      Weff, 512L * 512, x, 512L * 4096, d_out, 512L * 4096, bo, 4096);
}